// Round 1
// baseline (97.276 us; speedup 1.0000x reference)
//
#include <hip/hip_runtime.h>
#include <math.h>

// SurvLoss: Cox partial-likelihood loss with tie grouping.
// |Y| is an integer in [1,2000]; sorted order is -2000..-1,1..2000, so
//   loss2 = sum_t n_events(t) * log(negExpTotal + prefix_{u<=t} posExp(u))
//   loss1 = sum(Yhat * [Y>0]);  obs = count(Y>0)
// => 2000-bucket histogram + tiny double-precision scan. No sort.
//
// R2: replaced the 2M contended device-scope atomics (512 blocks flushing
// into one 16 KB histogram across 8 XCDs) with non-atomic per-block
// histogram dumps (8 MB streaming) + a tiled tree-reduce kernel whose
// final merge is only 131K atomics with 32 contenders/address.
//
// R3 (this round): unchanged resubmit — previous bench was an MI355X
// container infra failure; need baseline counters before editing.

#define NBLK 512
#define NT 256
#define NH 2048

__global__ __launch_bounds__(NT) void surv_hist(
    const float* __restrict__ Yhat, const float* __restrict__ Y, int n4,
    float* __restrict__ Exp, unsigned int* __restrict__ Evt,
    double* __restrict__ negPart, double* __restrict__ loss1Part,
    unsigned long long* __restrict__ obsPart)
{
    __shared__ float sExp[NH];
    __shared__ unsigned int sEvt[NH];
    for (int i = threadIdx.x; i < NH; i += NT) { sExp[i] = 0.f; sEvt[i] = 0u; }
    __syncthreads();

    float negSum = 0.f, loss1 = 0.f;
    unsigned int obs = 0;

    const float4* __restrict__ Y4 = (const float4*)Y;
    const float4* __restrict__ H4 = (const float4*)Yhat;
    const int stride = NBLK * NT;
    for (int i = blockIdx.x * NT + threadIdx.x; i < n4; i += stride) {
        float4 y = Y4[i];
        float4 h = H4[i];
        float ys[4] = {y.x, y.y, y.z, y.w};
        float hs[4] = {h.x, h.y, h.z, h.w};
        #pragma unroll
        for (int c = 0; c < 4; ++c) {
            float e = __expf(hs[c]);
            if (ys[c] > 0.f) {
                int t = (int)ys[c];           // t in [1,2000] < NH
                atomicAdd(&sExp[t], e);       // LDS atomic, random bucket
                atomicAdd(&sEvt[t], 1u);
                loss1 += hs[c];
                obs += 1u;
            } else {
                negSum += e;
            }
        }
    }

    // wave (64-lane) reduce of scalars
    #pragma unroll
    for (int off = 32; off > 0; off >>= 1) {
        negSum += __shfl_down(negSum, off);
        loss1  += __shfl_down(loss1, off);
        obs    += __shfl_down(obs, off);
    }
    __shared__ float wNeg[NT / 64], wL1[NT / 64];
    __shared__ unsigned int wObs[NT / 64];
    const int lane = threadIdx.x & 63, wid = threadIdx.x >> 6;
    if (lane == 0) { wNeg[wid] = negSum; wL1[wid] = loss1; wObs[wid] = obs; }
    __syncthreads();  // also guarantees all LDS hist atomics are complete
    if (threadIdx.x == 0) {
        double nn = 0.0, ll = 0.0; unsigned long long oo = 0ull;
        #pragma unroll
        for (int w = 0; w < NT / 64; ++w) {
            nn += (double)wNeg[w]; ll += (double)wL1[w]; oo += wObs[w];
        }
        negPart[blockIdx.x] = nn;
        loss1Part[blockIdx.x] = ll;
        obsPart[blockIdx.x] = oo;
    }

    // non-atomic coalesced dump of this block's histogram row
    float* __restrict__ myExp = Exp + (size_t)blockIdx.x * NH;
    unsigned int* __restrict__ myEvt = Evt + (size_t)blockIdx.x * NH;
    for (int i = threadIdx.x; i < NH; i += NT) {
        myExp[i] = sExp[i];
        myEvt[i] = sEvt[i];
    }
}

// Sum the 512 x 2048 per-block histograms down to one 2048-bucket histogram.
// Grid = 256 blocks: 8 column-chunks (256 cols each) x 32 row-chunks (16 rows).
// One atomicAdd per thread per array -> only 32 contenders per address.
__global__ __launch_bounds__(NT) void surv_reduce(
    const float* __restrict__ Exp, const unsigned int* __restrict__ Evt,
    float* __restrict__ gExp, unsigned int* __restrict__ gEvt)
{
    const int col = (blockIdx.x & 7) * NT + threadIdx.x;
    const int r0 = (blockIdx.x >> 3) * 16;
    float a = 0.f;
    unsigned int c = 0u;
    #pragma unroll
    for (int r = 0; r < 16; ++r) {
        a += Exp[(size_t)(r0 + r) * NH + col];
        c += Evt[(size_t)(r0 + r) * NH + col];
    }
    atomicAdd(&gExp[col], a);
    atomicAdd(&gEvt[col], c);
}

__global__ __launch_bounds__(NT) void surv_final(
    const float* __restrict__ gExp, const unsigned int* __restrict__ gEvt,
    const double* __restrict__ negPart, const double* __restrict__ loss1Part,
    const unsigned long long* __restrict__ obsPart, float* __restrict__ out)
{
    const int tid = threadIdx.x;
    __shared__ double sA[NT];

    // reduce per-block scalar partials (NBLK == 2*NT)
    double nP = negPart[tid] + negPart[tid + NT];
    double lP = loss1Part[tid] + loss1Part[tid + NT];
    double oP = (double)(obsPart[tid] + obsPart[tid + NT]);

    sA[tid] = nP; __syncthreads();
    for (int off = NT / 2; off > 0; off >>= 1) { if (tid < off) sA[tid] += sA[tid + off]; __syncthreads(); }
    const double negTotal = sA[0]; __syncthreads();

    sA[tid] = lP; __syncthreads();
    for (int off = NT / 2; off > 0; off >>= 1) { if (tid < off) sA[tid] += sA[tid + off]; __syncthreads(); }
    const double loss1 = sA[0]; __syncthreads();

    sA[tid] = oP; __syncthreads();
    for (int off = NT / 2; off > 0; off >>= 1) { if (tid < off) sA[tid] += sA[tid + off]; __syncthreads(); }
    const double obs = sA[0]; __syncthreads();

    // each thread owns 8 consecutive buckets (ascending t across threads)
    const int C = NH / NT;  // 8
    double pe[C]; unsigned int ev[C];
    double csum = 0.0;
    const int base = tid * C;
    #pragma unroll
    for (int j = 0; j < C; ++j) {
        pe[j] = (double)gExp[base + j];
        ev[j] = gEvt[base + j];
        csum += pe[j];
    }

    // Hillis-Steele inclusive scan of per-thread chunk sums (double)
    sA[tid] = csum; __syncthreads();
    for (int off = 1; off < NT; off <<= 1) {
        double add = (tid >= off) ? sA[tid - off] : 0.0;
        __syncthreads();
        sA[tid] += add;
        __syncthreads();
    }
    const double excl = sA[tid] - csum;
    __syncthreads();

    double prefix = negTotal + excl;
    double loss2 = 0.0;
    #pragma unroll
    for (int j = 0; j < C; ++j) {
        prefix += pe[j];
        if (ev[j]) loss2 += (double)ev[j] * log(prefix);
    }

    sA[tid] = loss2; __syncthreads();
    for (int off = NT / 2; off > 0; off >>= 1) { if (tid < off) sA[tid] += sA[tid + off]; __syncthreads(); }
    if (tid == 0) out[0] = (float)((sA[0] - loss1) / obs);
}

extern "C" void kernel_launch(void* const* d_in, const int* in_sizes, int n_in,
                              void* d_out, int out_size, void* d_ws, size_t ws_size,
                              hipStream_t stream)
{
    const float* Yhat = (const float*)d_in[0];
    const float* Y    = (const float*)d_in[1];
    const int n = in_sizes[0];

    char* ws = (char*)d_ws;
    // layout: per-block hist dumps, then final histogram, then scalar partials
    float* Exp               = (float*)(ws);                         // 4 MB
    unsigned int* Evt        = (unsigned int*)(ws + (size_t)NBLK * NH * 4);  // 4 MB
    char* tail               = ws + 2ull * NBLK * NH * 4;
    float* gExp              = (float*)(tail);                       // 8 KB
    unsigned int* gEvt       = (unsigned int*)(tail + NH * 4);       // 8 KB
    double* negPart          = (double*)(tail + NH * 8);             // 4 KB
    double* loss1Part        = (double*)(tail + NH * 8 + NBLK * 8);  // 4 KB
    unsigned long long* obsPart = (unsigned long long*)(tail + NH * 8 + 2 * NBLK * 8);

    // zero only the atomically-merged final histogram (16 KB)
    hipMemsetAsync(tail, 0, NH * 8, stream);

    surv_hist<<<NBLK, NT, 0, stream>>>(Yhat, Y, n / 4, Exp, Evt,
                                       negPart, loss1Part, obsPart);
    surv_reduce<<<256, NT, 0, stream>>>(Exp, Evt, gExp, gEvt);
    surv_final<<<1, NT, 0, stream>>>(gExp, gEvt, negPart, loss1Part, obsPart,
                                     (float*)d_out);
}

// Round 2
// 95.182 us; speedup vs baseline: 1.0220x; 1.0220x over previous
//
#include <hip/hip_runtime.h>
#include <math.h>

// SurvLoss: Cox partial-likelihood loss with tie grouping.
// |Y| is an integer in [1,2000]; sorted order is -2000..-1,1..2000, so
//   loss2 = sum_t n_events(t) * log(negExpTotal + prefix_{u<=t} posExp(u))
//   loss1 = sum(Yhat * [Y>0]);  obs = count(Y>0)
// => 2000-bucket histogram + tiny double-precision scan. No sort.
//
// R2: non-atomic per-block histogram dumps + tiled tree-reduce.
// R4 (this round): occupancy fix for surv_hist (NT 256->1024, 2-deep
// pipelined loads -> 4 outstanding float4/thread); u16 event dump (max
// 8192 events/block < 65536, provably safe); memset dispatch folded into
// hist block 0; shfl-based surv_final (2 syncthreads instead of ~56).

#define NBLK 512
#define NT 1024      // hist block size
#define NTF 256      // final/reduce block size
#define NH 2048

__global__ __launch_bounds__(NT) void surv_hist(
    const float* __restrict__ Yhat, const float* __restrict__ Y, int n4,
    float* __restrict__ Exp, unsigned short* __restrict__ Evt,
    float* __restrict__ gExp, unsigned int* __restrict__ gEvt,
    double* __restrict__ negPart, double* __restrict__ loss1Part,
    unsigned long long* __restrict__ obsPart)
{
    __shared__ float sExp[NH];
    __shared__ unsigned int sEvt[NH];
    for (int i = threadIdx.x; i < NH; i += NT) { sExp[i] = 0.f; sEvt[i] = 0u; }
    // block 0 also zeroes the final merged histogram (read only by
    // surv_reduce, which is stream-ordered after this kernel -> no race)
    if (blockIdx.x == 0) {
        for (int i = threadIdx.x; i < NH; i += NT) { gExp[i] = 0.f; gEvt[i] = 0u; }
    }
    __syncthreads();

    float negSum = 0.f, loss1 = 0.f;
    unsigned int obs = 0;

    const float4* __restrict__ Y4 = (const float4*)Y;
    const float4* __restrict__ H4 = (const float4*)Yhat;
    const int stride = NBLK * NT;

#define PROC(yv, hv)                                     \
    {                                                    \
        float ys[4] = {yv.x, yv.y, yv.z, yv.w};          \
        float hs[4] = {hv.x, hv.y, hv.z, hv.w};          \
        _Pragma("unroll")                                \
        for (int c = 0; c < 4; ++c) {                    \
            float e = __expf(hs[c]);                     \
            if (ys[c] > 0.f) {                           \
                int t = (int)ys[c];                      \
                atomicAdd(&sExp[t], e);                  \
                atomicAdd(&sEvt[t], 1u);                 \
                loss1 += hs[c];                          \
                obs += 1u;                               \
            } else {                                     \
                negSum += e;                             \
            }                                            \
        }                                                \
    }

    int i = blockIdx.x * NT + threadIdx.x;
    // 2-deep pipelined main loop: 4 outstanding 16B loads per thread
    for (; i + stride < n4; i += 2 * stride) {
        float4 y0 = Y4[i];
        float4 h0 = H4[i];
        float4 y1 = Y4[i + stride];
        float4 h1 = H4[i + stride];
        PROC(y0, h0);
        PROC(y1, h1);
    }
    for (; i < n4; i += stride) {
        float4 y = Y4[i];
        float4 h = H4[i];
        PROC(y, h);
    }
#undef PROC

    // wave (64-lane) reduce of scalars
    #pragma unroll
    for (int off = 32; off > 0; off >>= 1) {
        negSum += __shfl_down(negSum, off);
        loss1  += __shfl_down(loss1, off);
        obs    += __shfl_down(obs, off);
    }
    __shared__ float wNeg[NT / 64], wL1[NT / 64];
    __shared__ unsigned int wObs[NT / 64];
    const int lane = threadIdx.x & 63, wid = threadIdx.x >> 6;
    if (lane == 0) { wNeg[wid] = negSum; wL1[wid] = loss1; wObs[wid] = obs; }
    __syncthreads();  // also guarantees all LDS hist atomics are complete
    if (threadIdx.x == 0) {
        double nn = 0.0, ll = 0.0; unsigned long long oo = 0ull;
        #pragma unroll
        for (int w = 0; w < NT / 64; ++w) {
            nn += (double)wNeg[w]; ll += (double)wL1[w]; oo += wObs[w];
        }
        negPart[blockIdx.x] = nn;
        loss1Part[blockIdx.x] = ll;
        obsPart[blockIdx.x] = oo;
    }

    // non-atomic coalesced dump of this block's histogram row
    float* __restrict__ myExp = Exp + (size_t)blockIdx.x * NH;
    unsigned short* __restrict__ myEvt = Evt + (size_t)blockIdx.x * NH;
    for (int i2 = threadIdx.x; i2 < NH; i2 += NT) {
        myExp[i2] = sExp[i2];
        myEvt[i2] = (unsigned short)sEvt[i2];  // <=8192 events/block, fits u16
    }
}

// Sum the 512 x 2048 per-block histograms down to one 2048-bucket histogram.
// Grid = 512 blocks: 8 column-chunks (256 cols each) x 64 row-chunks (8 rows).
// One atomicAdd per thread per array -> 64 contenders per address.
__global__ __launch_bounds__(NTF) void surv_reduce(
    const float* __restrict__ Exp, const unsigned short* __restrict__ Evt,
    float* __restrict__ gExp, unsigned int* __restrict__ gEvt)
{
    const int col = (blockIdx.x & 7) * NTF + threadIdx.x;
    const int r0 = (blockIdx.x >> 3) * 8;
    float a = 0.f;
    unsigned int c = 0u;
    #pragma unroll
    for (int r = 0; r < 8; ++r) {
        a += Exp[(size_t)(r0 + r) * NH + col];
        c += (unsigned int)Evt[(size_t)(r0 + r) * NH + col];
    }
    atomicAdd(&gExp[col], a);
    atomicAdd(&gEvt[col], c);
}

__global__ __launch_bounds__(NTF) void surv_final(
    const float* __restrict__ gExp, const unsigned int* __restrict__ gEvt,
    const double* __restrict__ negPart, const double* __restrict__ loss1Part,
    const unsigned long long* __restrict__ obsPart, float* __restrict__ out)
{
    const int tid = threadIdx.x;            // NTF = 256
    const int lane = tid & 63, wid = tid >> 6;

    // reduce per-block scalar partials (NBLK == 2*NTF), shfl within wave
    double nP = negPart[tid] + negPart[tid + NTF];
    double lP = loss1Part[tid] + loss1Part[tid + NTF];
    double oP = (double)(obsPart[tid] + obsPart[tid + NTF]);
    #pragma unroll
    for (int off = 32; off > 0; off >>= 1) {
        nP += __shfl_down(nP, off);
        lP += __shfl_down(lP, off);
        oP += __shfl_down(oP, off);
    }
    __shared__ double sN[4], sL[4], sO[4], sW[4], sZ[4];
    if (lane == 0) { sN[wid] = nP; sL[wid] = lP; sO[wid] = oP; }

    // each thread owns 8 consecutive buckets (ascending t across threads)
    const int C = NH / NTF;  // 8
    double pe[C]; unsigned int ev[C];
    double csum = 0.0;
    const int base = tid * C;
    #pragma unroll
    for (int j = 0; j < C; ++j) {
        pe[j] = (double)gExp[base + j];
        ev[j] = gEvt[base + j];
        csum += pe[j];
    }

    // wave-inclusive shfl scan of per-thread chunk sums
    double x = csum;
    #pragma unroll
    for (int off = 1; off < 64; off <<= 1) {
        double t = __shfl_up(x, off);
        if (lane >= off) x += t;
    }
    if (lane == 63) sW[wid] = x;
    __syncthreads();

    const double negTotal = sN[0] + sN[1] + sN[2] + sN[3];
    const double loss1    = sL[0] + sL[1] + sL[2] + sL[3];
    const double obs      = sO[0] + sO[1] + sO[2] + sO[3];
    double waveOff = 0.0;
    for (int w = 0; w < wid; ++w) waveOff += sW[w];

    double prefix = negTotal + waveOff + (x - csum);  // exclusive prefix
    double loss2 = 0.0;
    #pragma unroll
    for (int j = 0; j < C; ++j) {
        prefix += pe[j];
        if (ev[j]) loss2 += (double)ev[j] * log(prefix);
    }

    #pragma unroll
    for (int off = 32; off > 0; off >>= 1) loss2 += __shfl_down(loss2, off);
    if (lane == 0) sZ[wid] = loss2;
    __syncthreads();
    if (tid == 0)
        out[0] = (float)((sZ[0] + sZ[1] + sZ[2] + sZ[3] - loss1) / obs);
}

extern "C" void kernel_launch(void* const* d_in, const int* in_sizes, int n_in,
                              void* d_out, int out_size, void* d_ws, size_t ws_size,
                              hipStream_t stream)
{
    const float* Yhat = (const float*)d_in[0];
    const float* Y    = (const float*)d_in[1];
    const int n = in_sizes[0];

    char* ws = (char*)d_ws;
    // layout: per-block hist dumps, then final histogram, then scalar partials
    float* Exp            = (float*)(ws);                                   // 4 MB
    unsigned short* Evt   = (unsigned short*)(ws + (size_t)NBLK * NH * 4);  // 2 MB
    char* tail            = ws + (size_t)NBLK * NH * 6;
    float* gExp           = (float*)(tail);                                 // 8 KB
    unsigned int* gEvt    = (unsigned int*)(tail + NH * 4);                 // 8 KB
    double* negPart       = (double*)(tail + NH * 8);                       // 4 KB
    double* loss1Part     = (double*)(tail + NH * 8 + NBLK * 8);            // 4 KB
    unsigned long long* obsPart = (unsigned long long*)(tail + NH * 8 + 2 * NBLK * 8);

    surv_hist<<<NBLK, NT, 0, stream>>>(Yhat, Y, n / 4, Exp, Evt,
                                       gExp, gEvt, negPart, loss1Part, obsPart);
    surv_reduce<<<512, NTF, 0, stream>>>(Exp, Evt, gExp, gEvt);
    surv_final<<<1, NTF, 0, stream>>>(gExp, gEvt, negPart, loss1Part, obsPart,
                                      (float*)d_out);
}